// Round 1
// baseline (1211.876 us; speedup 1.0000x reference)
//
#include <hip/hip_runtime.h>

#define N_NODES 100000
#define N_EDGES 1600000
#define NFEAT 64
#define NGRAPHS 256
#define BN_EPS 1e-5f

// ---- helpers ----------------------------------------------------------------

__device__ __forceinline__ unsigned f2ord(float f) {
  // order-preserving map float -> uint (for atomicMax-based segment_max)
  unsigned u = __float_as_uint(f);
  return (u & 0x80000000u) ? ~u : (u | 0x80000000u);
}

__device__ __forceinline__ float ord2f(unsigned u) {
  unsigned bits = (u & 0x80000000u) ? (u ^ 0x80000000u) : ~u;
  return __uint_as_float(bits);
}

// Detect whether edge_index is int64 (high dwords all zero) or int32.
__global__ void detect_i64(const unsigned* __restrict__ ei, int* __restrict__ flag) {
  if (blockIdx.x == 0 && threadIdx.x == 0) {
    int f = 1;
    for (int i = 1; i < 64; i += 2) {
      if (ei[i] != 0u) { f = 0; break; }
    }
    *flag = f;
  }
}

// ---- GEMM: C[N][64] = act(A)[N][64] @ W[64][64] -----------------------------

template<bool RELU>
__global__ __launch_bounds__(256) void gemm64(const float* __restrict__ A,
                                              const float* __restrict__ W,
                                              float* __restrict__ C, int N) {
  __shared__ float Wt[64][68];   // W transposed: Wt[c][k], pad to 68 for f4 alignment
  __shared__ float At[64][68];   // A tile (relu applied at staging)
  const int tid = threadIdx.x;
  const int rowBase = blockIdx.x * 64;

  // stage W transposed
  for (int i = tid; i < 4096; i += 256) {
    int k = i >> 6, c = i & 63;
    Wt[c][k] = W[i];
  }
  // stage A tile (coalesced float4), relu fused
  const float4* A4 = (const float4*)A;
  #pragma unroll
  for (int j = 0; j < 4; ++j) {
    int t4 = tid + j * 256;                 // 0..1023 float4s of the tile
    int g4 = rowBase * 16 + t4;
    float4 v = make_float4(0.f, 0.f, 0.f, 0.f);
    if (g4 < N * 16) v = A4[g4];
    if (RELU) {
      v.x = fmaxf(v.x, 0.f); v.y = fmaxf(v.y, 0.f);
      v.z = fmaxf(v.z, 0.f); v.w = fmaxf(v.w, 0.f);
    }
    int r = t4 >> 4, k4 = t4 & 15;
    *(float4*)&At[r][k4 * 4] = v;
  }
  __syncthreads();

  const int c = tid & 63;
  const int r0 = (tid >> 6) * 16;
  float acc[16];
  #pragma unroll
  for (int i = 0; i < 16; ++i) acc[i] = 0.f;

  for (int k0 = 0; k0 < 64; k0 += 4) {
    float4 w = *(const float4*)&Wt[c][k0];
    #pragma unroll
    for (int i = 0; i < 16; ++i) {
      float4 a = *(const float4*)&At[r0 + i][k0];   // wave-broadcast read
      acc[i] += a.x * w.x + a.y * w.y + a.z * w.z + a.w * w.w;
    }
  }

  #pragma unroll
  for (int i = 0; i < 16; ++i) {
    int row = rowBase + r0 + i;
    if (row < N) C[row * 64 + c] = acc[i];
  }
}

// ---- init agg with bias -----------------------------------------------------

__global__ __launch_bounds__(256) void init_bias(float* __restrict__ agg,
                                                 const float* __restrict__ b, int n4) {
  int i = blockIdx.x * 256 + threadIdx.x;   // float4 index
  if (i >= n4) return;
  ((float4*)agg)[i] = ((const float4*)b)[i & 15];
}

// ---- edge scatter: agg[dst] += ew * h[src] ----------------------------------

__global__ __launch_bounds__(256) void scatter_add(const float* __restrict__ h,
                                                   const void* __restrict__ eiPtr,
                                                   const int* __restrict__ flag,
                                                   const float* __restrict__ ew,
                                                   float* __restrict__ agg) {
  int gtid = blockIdx.x * 256 + threadIdx.x;
  int e = gtid >> 6, lane = gtid & 63;
  if (e >= N_EDGES) return;
  int s, d;
  if (*flag) {
    const long long* ei = (const long long*)eiPtr;
    s = (int)ei[e]; d = (int)ei[N_EDGES + e];
  } else {
    const int* ei = (const int*)eiPtr;
    s = ei[e]; d = ei[N_EDGES + e];
  }
  float v = ew[e] * h[s * 64 + lane];
  atomicAdd(&agg[d * 64 + lane], v);
}

// ---- segment max into ordered-uint pooled -----------------------------------

__global__ __launch_bounds__(256) void seg_max(const float* __restrict__ h,
                                               const void* __restrict__ bPtr,
                                               const int* __restrict__ flag,
                                               unsigned* __restrict__ pooled) {
  int gtid = blockIdx.x * 256 + threadIdx.x;
  int n = gtid >> 6, lane = gtid & 63;
  if (n >= N_NODES) return;
  int g = (*flag) ? (int)((const long long*)bPtr)[n] : ((const int*)bPtr)[n];
  atomicMax(&pooled[g * 64 + lane], f2ord(h[n * 64 + lane]));
}

// ---- BatchNorm (training-mode batch stats) + linear head --------------------

__global__ __launch_bounds__(256) void bn_head(const unsigned* __restrict__ pooled,
                                               const float* __restrict__ gamma,
                                               const float* __restrict__ beta,
                                               const float* __restrict__ linW,
                                               const float* __restrict__ linb,
                                               float* __restrict__ out) {
  __shared__ float P[NGRAPHS][64 + 1];
  __shared__ float mean_s[64], rstd_s[64];
  const int tid = threadIdx.x;

  for (int i = tid; i < NGRAPHS * 64; i += 256) {
    P[i >> 6][i & 63] = ord2f(pooled[i]);
  }
  __syncthreads();

  if (tid < 64) {
    float s = 0.f, ss = 0.f;
    for (int g = 0; g < NGRAPHS; ++g) {
      float v = P[g][tid];
      s += v; ss += v * v;
    }
    float m = s / (float)NGRAPHS;
    float var = ss / (float)NGRAPHS - m * m;   // biased variance (jnp.var default)
    mean_s[tid] = m;
    rstd_s[tid] = rsqrtf(var + BN_EPS);
  }
  __syncthreads();

  float acc = linb[0];
  #pragma unroll 8
  for (int c = 0; c < 64; ++c) {
    float normed = (P[tid][c] - mean_s[c]) * rstd_s[c] * gamma[c] + beta[c];
    acc += normed * linW[c];
  }
  out[tid] = acc;
}

// ---- launch -----------------------------------------------------------------

extern "C" void kernel_launch(void* const* d_in, const int* in_sizes, int n_in,
                              void* d_out, int out_size, void* d_ws, size_t ws_size,
                              hipStream_t stream) {
  const float* x     = (const float*)d_in[0];
  const void*  ei    = d_in[1];
  const float* ew    = (const float*)d_in[2];
  const void*  batch = d_in[3];
  const float* W1    = (const float*)d_in[4];
  const float* b1    = (const float*)d_in[5];
  const float* W2    = (const float*)d_in[6];
  const float* b2    = (const float*)d_in[7];
  const float* W3    = (const float*)d_in[8];
  const float* b3    = (const float*)d_in[9];
  const float* gamma = (const float*)d_in[10];
  const float* beta  = (const float*)d_in[11];
  const float* linW  = (const float*)d_in[12];
  const float* linb  = (const float*)d_in[13];

  char* ws = (char*)d_ws;
  const size_t matBytes = (size_t)N_NODES * 64 * sizeof(float);
  float*    h      = (float*)ws;
  float*    agg    = (float*)(ws + matBytes);
  unsigned* pooled = (unsigned*)(ws + 2 * matBytes);
  int*      flag   = (int*)(ws + 2 * matBytes + (size_t)NGRAPHS * 64 * sizeof(unsigned));

  detect_i64<<<1, 64, 0, stream>>>((const unsigned*)ei, flag);

  const int gemmBlocks = (N_NODES + 63) / 64;
  const int scatBlocks = (N_EDGES * 64) / 256;        // exact
  const int n4         = N_NODES * 16;                // float4 count of [N][64]
  const int initBlocks = (n4 + 255) / 256;
  const int segBlocks  = (N_NODES * 64) / 256;        // exact

  // layer 1
  gemm64<false><<<gemmBlocks, 256, 0, stream>>>(x, W1, h, N_NODES);
  init_bias<<<initBlocks, 256, 0, stream>>>(agg, b1, n4);
  scatter_add<<<scatBlocks, 256, 0, stream>>>(h, ei, flag, ew, agg);
  // layer 2 (relu on read)
  gemm64<true><<<gemmBlocks, 256, 0, stream>>>(agg, W2, h, N_NODES);
  init_bias<<<initBlocks, 256, 0, stream>>>(agg, b2, n4);
  scatter_add<<<scatBlocks, 256, 0, stream>>>(h, ei, flag, ew, agg);
  // layer 3 (relu on read, no relu after)
  gemm64<true><<<gemmBlocks, 256, 0, stream>>>(agg, W3, h, N_NODES);
  init_bias<<<initBlocks, 256, 0, stream>>>(agg, b3, n4);
  scatter_add<<<scatBlocks, 256, 0, stream>>>(h, ei, flag, ew, agg);

  // pooling + BN + head
  hipMemsetAsync(pooled, 0, (size_t)NGRAPHS * 64 * sizeof(unsigned), stream);
  seg_max<<<segBlocks, 256, 0, stream>>>(agg, batch, flag, pooled);
  bn_head<<<1, 256, 0, stream>>>(pooled, gamma, beta, linW, linb, (float*)d_out);
}

// Round 2
// 621.323 us; speedup vs baseline: 1.9505x; 1.9505x over previous
//
#include <hip/hip_runtime.h>

#define N_NODES 100000
#define N_EDGES 1600000
#define NGRAPHS 256
#define BN_EPS 1e-5f
#define SCAN_NBLK ((N_NODES + 1023) / 1024)   // 98

// ---- helpers ----------------------------------------------------------------

__device__ __forceinline__ unsigned f2ord(float f) {
  unsigned u = __float_as_uint(f);
  return (u & 0x80000000u) ? ~u : (u | 0x80000000u);
}

__device__ __forceinline__ float ord2f(unsigned u) {
  unsigned bits = (u & 0x80000000u) ? (u ^ 0x80000000u) : ~u;
  return __uint_as_float(bits);
}

// Detect whether edge_index is int64 (high dwords all zero) or int32.
__global__ void detect_i64(const unsigned* __restrict__ ei, int* __restrict__ flag) {
  if (blockIdx.x == 0 && threadIdx.x == 0) {
    int f = 1;
    for (int i = 1; i < 64; i += 2) {
      if (ei[i] != 0u) { f = 0; break; }
    }
    *flag = f;
  }
}

__device__ __forceinline__ int load_idx(const void* p, const int* flag, int i) {
  return (*flag) ? (int)((const long long*)p)[i] : ((const int*)p)[i];
}

// ---- CSR build --------------------------------------------------------------

__global__ __launch_bounds__(256) void edge_hist(const void* __restrict__ eiPtr,
                                                 const int* __restrict__ flag,
                                                 int* __restrict__ counts) {
  int e = blockIdx.x * 256 + threadIdx.x;
  if (e >= N_EDGES) return;
  int d = load_idx(eiPtr, flag, N_EDGES + e);
  atomicAdd(&counts[d], 1);
}

// scan1: per-1024-chunk exclusive scan into rowPtr (partial) + chunk totals
__global__ __launch_bounds__(256) void scan1(const int* __restrict__ counts,
                                             int* __restrict__ partial,
                                             int* __restrict__ blockSums) {
  __shared__ int lds[256];
  const int tid = threadIdx.x;
  const int idx = blockIdx.x * 1024 + tid * 4;
  int c0 = 0, c1 = 0, c2 = 0, c3 = 0;
  if (idx + 3 < N_NODES) {
    int4 c = *(const int4*)&counts[idx];
    c0 = c.x; c1 = c.y; c2 = c.z; c3 = c.w;
  } else {
    if (idx     < N_NODES) c0 = counts[idx];
    if (idx + 1 < N_NODES) c1 = counts[idx + 1];
    if (idx + 2 < N_NODES) c2 = counts[idx + 2];
    if (idx + 3 < N_NODES) c3 = counts[idx + 3];
  }
  int s0 = c0, s1 = s0 + c1, s2 = s1 + c2, s3 = s2 + c3;
  lds[tid] = s3;
  __syncthreads();
  for (int off = 1; off < 256; off <<= 1) {
    int t = (tid >= off) ? lds[tid - off] : 0;
    __syncthreads();
    lds[tid] += t;
    __syncthreads();
  }
  int excl = lds[tid] - s3;
  if (idx     < N_NODES) partial[idx]     = excl;
  if (idx + 1 < N_NODES) partial[idx + 1] = excl + s0;
  if (idx + 2 < N_NODES) partial[idx + 2] = excl + s1;
  if (idx + 3 < N_NODES) partial[idx + 3] = excl + s2;
  if (tid == 255) blockSums[blockIdx.x] = lds[255];
}

__global__ void scan2(int* __restrict__ blockSums) {
  __shared__ int lds[256];
  const int tid = threadIdx.x;
  lds[tid] = (tid < SCAN_NBLK) ? blockSums[tid] : 0;
  __syncthreads();
  int own = lds[tid];
  for (int off = 1; off < 256; off <<= 1) {
    int t = (tid >= off) ? lds[tid - off] : 0;
    __syncthreads();
    lds[tid] += t;
    __syncthreads();
  }
  if (tid < SCAN_NBLK) blockSums[tid] = lds[tid] - own;  // exclusive
}

__global__ __launch_bounds__(256) void scan3(int* __restrict__ rowPtr,
                                             const int* __restrict__ blockSums,
                                             int* __restrict__ cursor) {
  int i = blockIdx.x * 256 + threadIdx.x;
  if (i >= N_NODES) return;
  int v = rowPtr[i] + blockSums[i >> 10];
  rowPtr[i] = v;
  cursor[i] = v;
  if (i == 0) rowPtr[N_NODES] = N_EDGES;
}

__global__ __launch_bounds__(256) void fill_csr(const void* __restrict__ eiPtr,
                                                const int* __restrict__ flag,
                                                const float* __restrict__ ew,
                                                int* __restrict__ cursor,
                                                int2* __restrict__ csrSW) {
  int e = blockIdx.x * 256 + threadIdx.x;
  if (e >= N_EDGES) return;
  int s = load_idx(eiPtr, flag, e);
  int d = load_idx(eiPtr, flag, N_EDGES + e);
  int pos = atomicAdd(&cursor[d], 1);
  int2 r; r.x = s; r.y = __float_as_int(ew[e]);
  csrSW[pos] = r;
}

// ---- pull aggregation: out[n] = sum_{e: dst=n} w_e * h[src_e] ---------------

__global__ __launch_bounds__(256) void pull_agg(const float* __restrict__ h,
                                                const int* __restrict__ rowPtr,
                                                const int2* __restrict__ csrSW,
                                                float* __restrict__ out) {
  int gtid = blockIdx.x * 256 + threadIdx.x;
  int n = gtid >> 6, lane = gtid & 63;
  if (n >= N_NODES) return;
  int beg = rowPtr[n], end = rowPtr[n + 1];
  float acc = 0.f;
  int i = beg;
  for (; i + 2 <= end; i += 2) {
    int2 a = csrSW[i];
    int2 b = csrSW[i + 1];
    float va = h[a.x * 64 + lane];
    float vb = h[b.x * 64 + lane];
    acc += __int_as_float(a.y) * va;
    acc += __int_as_float(b.y) * vb;
  }
  if (i < end) {
    int2 a = csrSW[i];
    acc += __int_as_float(a.y) * h[a.x * 64 + lane];
  }
  out[n * 64 + lane] = acc;
}

// ---- GEMM: C[N][64] = A[N][64] @ W[64][64] + b (opt relu), in-place safe ----

template<bool RELU_OUT>
__global__ __launch_bounds__(256) void gemm64(const float* A,
                                              const float* __restrict__ W,
                                              const float* __restrict__ b,
                                              float* C, int N) {
  __shared__ float Wt[64][68];
  __shared__ float At[64][68];
  const int tid = threadIdx.x;
  const int rowBase = blockIdx.x * 64;

  for (int i = tid; i < 4096; i += 256) {
    int k = i >> 6, c = i & 63;
    Wt[c][k] = W[i];
  }
  const float4* A4 = (const float4*)A;
  #pragma unroll
  for (int j = 0; j < 4; ++j) {
    int t4 = tid + j * 256;
    int g4 = rowBase * 16 + t4;
    float4 v = make_float4(0.f, 0.f, 0.f, 0.f);
    if (g4 < N * 16) v = A4[g4];
    int r = t4 >> 4, k4 = t4 & 15;
    *(float4*)&At[r][k4 * 4] = v;
  }
  __syncthreads();

  const int c = tid & 63;
  const int r0 = (tid >> 6) * 16;
  float acc[16];
  #pragma unroll
  for (int i = 0; i < 16; ++i) acc[i] = 0.f;

  for (int k0 = 0; k0 < 64; k0 += 4) {
    float4 w = *(const float4*)&Wt[c][k0];
    #pragma unroll
    for (int i = 0; i < 16; ++i) {
      float4 a = *(const float4*)&At[r0 + i][k0];
      acc[i] += a.x * w.x + a.y * w.y + a.z * w.z + a.w * w.w;
    }
  }

  const float bias = b[c];
  #pragma unroll
  for (int i = 0; i < 16; ++i) {
    int row = rowBase + r0 + i;
    if (row < N) {
      float v = acc[i] + bias;
      if (RELU_OUT) v = fmaxf(v, 0.f);
      C[row * 64 + c] = v;
    }
  }
}

// ---- fallback path (small ws): bias-init + atomic scatter -------------------

__global__ __launch_bounds__(256) void init_bias(float* __restrict__ agg,
                                                 const float* __restrict__ b, int n4) {
  int i = blockIdx.x * 256 + threadIdx.x;
  if (i >= n4) return;
  ((float4*)agg)[i] = ((const float4*)b)[i & 15];
}

template<bool RELU_IN>
__global__ __launch_bounds__(256) void scatter_add(const float* __restrict__ h,
                                                   const void* __restrict__ eiPtr,
                                                   const int* __restrict__ flag,
                                                   const float* __restrict__ ew,
                                                   float* __restrict__ agg) {
  int gtid = blockIdx.x * 256 + threadIdx.x;
  int e = gtid >> 6, lane = gtid & 63;
  if (e >= N_EDGES) return;
  int s = load_idx(eiPtr, flag, e);
  int d = load_idx(eiPtr, flag, N_EDGES + e);
  float v = h[s * 64 + lane];
  if (RELU_IN) v = fmaxf(v, 0.f);
  atomicAdd(&agg[d * 64 + lane], ew[e] * v);
}

// ---- segment max ------------------------------------------------------------

__global__ __launch_bounds__(256) void seg_max(const float* __restrict__ h,
                                               const void* __restrict__ bPtr,
                                               const int* __restrict__ flag,
                                               unsigned* __restrict__ pooled) {
  int gtid = blockIdx.x * 256 + threadIdx.x;
  int n = gtid >> 6, lane = gtid & 63;
  if (n >= N_NODES) return;
  int g = load_idx(bPtr, flag, n);
  atomicMax(&pooled[g * 64 + lane], f2ord(h[n * 64 + lane]));
}

// ---- BatchNorm + linear head ------------------------------------------------

__global__ __launch_bounds__(256) void bn_head(const unsigned* __restrict__ pooled,
                                               const float* __restrict__ gamma,
                                               const float* __restrict__ beta,
                                               const float* __restrict__ linW,
                                               const float* __restrict__ linb,
                                               float* __restrict__ out) {
  __shared__ float P[NGRAPHS][64 + 1];
  __shared__ float mean_s[64], rstd_s[64];
  const int tid = threadIdx.x;

  for (int i = tid; i < NGRAPHS * 64; i += 256) {
    P[i >> 6][i & 63] = ord2f(pooled[i]);
  }
  __syncthreads();

  if (tid < 64) {
    float s = 0.f, ss = 0.f;
    for (int g = 0; g < NGRAPHS; ++g) {
      float v = P[g][tid];
      s += v; ss += v * v;
    }
    float m = s / (float)NGRAPHS;
    float var = ss / (float)NGRAPHS - m * m;
    mean_s[tid] = m;
    rstd_s[tid] = rsqrtf(var + BN_EPS);
  }
  __syncthreads();

  float acc = linb[0];
  #pragma unroll 8
  for (int c = 0; c < 64; ++c) {
    float normed = (P[tid][c] - mean_s[c]) * rstd_s[c] * gamma[c] + beta[c];
    acc += normed * linW[c];
  }
  out[tid] = acc;
}

// ---- launch -----------------------------------------------------------------

extern "C" void kernel_launch(void* const* d_in, const int* in_sizes, int n_in,
                              void* d_out, int out_size, void* d_ws, size_t ws_size,
                              hipStream_t stream) {
  const float* x     = (const float*)d_in[0];
  const void*  ei    = d_in[1];
  const float* ew    = (const float*)d_in[2];
  const void*  batch = d_in[3];
  const float* W1    = (const float*)d_in[4];
  const float* b1    = (const float*)d_in[5];
  const float* W2    = (const float*)d_in[6];
  const float* b2    = (const float*)d_in[7];
  const float* W3    = (const float*)d_in[8];
  const float* b3    = (const float*)d_in[9];
  const float* gamma = (const float*)d_in[10];
  const float* beta  = (const float*)d_in[11];
  const float* linW  = (const float*)d_in[12];
  const float* linb  = (const float*)d_in[13];

  char* ws = (char*)d_ws;
  const size_t MAT = (size_t)N_NODES * 64 * sizeof(float);          // 25.6 MB
  const size_t CSR = (size_t)N_EDGES * sizeof(int2);                // 12.8 MB
  const size_t PTR = ((size_t)(N_NODES + 1) * sizeof(int) + 255) & ~(size_t)255;

  size_t off = 0;
  float* t      = (float*)(ws + off); off += MAT;
  float* u      = (float*)(ws + off); off += MAT;
  const size_t csrOff = off;
  int2*  csrSW  = (int2*)(ws + off); off += CSR;
  int*   rowPtr = (int*)(ws + off);  off += PTR;
  int*   cursor = (int*)(ws + off);  off += PTR;
  int*   bsums  = (int*)(ws + off);  off += 1024;
  unsigned* pooled = (unsigned*)(ws + off); off += (size_t)NGRAPHS * 64 * sizeof(unsigned);
  int*   flag   = (int*)(ws + off);  off += 256;
  const bool csrPath = (ws_size >= off);

  const int gemmBlocks = (N_NODES + 63) / 64;
  const int edgeBlocks = (N_EDGES + 255) / 256;
  const int nodeWaveBlocks = (N_NODES * 64) / 256;   // exact: 25000

  detect_i64<<<1, 64, 0, stream>>>((const unsigned*)ei, flag);

  if (csrPath) {
    // ---- build CSR (once; reused by all 3 layers) ----
    hipMemsetAsync(cursor, 0, (size_t)N_NODES * sizeof(int), stream);
    edge_hist<<<edgeBlocks, 256, 0, stream>>>(ei, flag, cursor);
    scan1<<<SCAN_NBLK, 256, 0, stream>>>(cursor, rowPtr, bsums);
    scan2<<<1, 256, 0, stream>>>(bsums);
    scan3<<<(N_NODES + 255) / 256, 256, 0, stream>>>(rowPtr, bsums, cursor);
    fill_csr<<<edgeBlocks, 256, 0, stream>>>(ei, flag, ew, cursor, csrSW);

    // layer 1: u = A·x ; u = relu(u@W1 + b1)
    pull_agg<<<nodeWaveBlocks, 256, 0, stream>>>(x, rowPtr, csrSW, u);
    gemm64<true><<<gemmBlocks, 256, 0, stream>>>(u, W1, b1, u, N_NODES);
    // layer 2
    pull_agg<<<nodeWaveBlocks, 256, 0, stream>>>(u, rowPtr, csrSW, t);
    gemm64<true><<<gemmBlocks, 256, 0, stream>>>(t, W2, b2, t, N_NODES);
    // layer 3 (no relu)
    pull_agg<<<nodeWaveBlocks, 256, 0, stream>>>(t, rowPtr, csrSW, u);
    gemm64<false><<<gemmBlocks, 256, 0, stream>>>(u, W3, b3, u, N_NODES);

    hipMemsetAsync(pooled, 0, (size_t)NGRAPHS * 64 * sizeof(unsigned), stream);
    seg_max<<<nodeWaveBlocks, 256, 0, stream>>>(u, batch, flag, pooled);
    bn_head<<<1, 256, 0, stream>>>(pooled, gamma, beta, linW, linb, (float*)d_out);
  } else {
    // ---- fallback: atomic scatter path (round-1 layout) ----
    float* h   = t;
    float* agg = u;
    unsigned* pooled2 = (unsigned*)(ws + 2 * MAT);
    int* flag2 = (int*)(ws + 2 * MAT + (size_t)NGRAPHS * 64 * sizeof(unsigned));
    detect_i64<<<1, 64, 0, stream>>>((const unsigned*)ei, flag2);
    const int n4 = N_NODES * 16;
    const int initBlocks = (n4 + 255) / 256;
    const int scatBlocks = (N_EDGES * 64) / 256;

    gemm64<false><<<gemmBlocks, 256, 0, stream>>>(x, W1, b1, h, N_NODES);
    init_bias<<<initBlocks, 256, 0, stream>>>(agg, b1, n4);
    scatter_add<false><<<scatBlocks, 256, 0, stream>>>(h, ei, flag2, ew, agg);
    gemm64<false><<<gemmBlocks, 256, 0, stream>>>(agg, W2, b2, h, N_NODES);
    // NOTE: fallback keeps pre-activation in agg; apply relu via scatter RELU_IN
    init_bias<<<initBlocks, 256, 0, stream>>>(agg, b2, n4);
    scatter_add<true><<<scatBlocks, 256, 0, stream>>>(h, ei, flag2, ew, agg);
    gemm64<false><<<gemmBlocks, 256, 0, stream>>>(agg, W3, b3, h, N_NODES);
    init_bias<<<initBlocks, 256, 0, stream>>>(agg, b3, n4);
    scatter_add<true><<<scatBlocks, 256, 0, stream>>>(h, ei, flag2, ew, agg);

    hipMemsetAsync(pooled2, 0, (size_t)NGRAPHS * 64 * sizeof(unsigned), stream);
    seg_max<<<nodeWaveBlocks, 256, 0, stream>>>(agg, batch, flag2, pooled2);
    bn_head<<<1, 256, 0, stream>>>(pooled2, gamma, beta, linW, linb, (float*)d_out);
  }
}

// Round 3
// 525.557 us; speedup vs baseline: 2.3059x; 1.1822x over previous
//
#include <hip/hip_runtime.h>

#define N_NODES 100000
#define N_EDGES 1600000
#define NGRAPHS 256
#define BN_EPS 1e-5f
#define SCAN_NBLK ((N_NODES + 1023) / 1024)   // 98
#define NBUK ((N_NODES + 511) >> 9)           // 196 buckets of 512 dst nodes
#define BIN_EPB 2048                          // edges per binpass block
#define BIN_BLOCKS ((N_EDGES + BIN_EPB - 1) / BIN_EPB)  // 782

// ---- helpers ----------------------------------------------------------------

__device__ __forceinline__ unsigned f2ord(float f) {
  unsigned u = __float_as_uint(f);
  return (u & 0x80000000u) ? ~u : (u | 0x80000000u);
}

__device__ __forceinline__ float ord2f(unsigned u) {
  unsigned bits = (u & 0x80000000u) ? (u ^ 0x80000000u) : ~u;
  return __uint_as_float(bits);
}

// Detect whether edge_index is int64 (high dwords all zero) or int32.
__global__ void detect_i64(const unsigned* __restrict__ ei, int* __restrict__ flag) {
  if (blockIdx.x == 0 && threadIdx.x == 0) {
    int f = 1;
    for (int i = 1; i < 64; i += 2) {
      if (ei[i] != 0u) { f = 0; break; }
    }
    *flag = f;
  }
}

__device__ __forceinline__ int load_idx(const void* p, const int* flag, long long i) {
  return (*flag) ? (int)((const long long*)p)[i] : ((const int*)p)[i];
}

// ---- CSR build --------------------------------------------------------------

__global__ __launch_bounds__(256) void edge_hist(const void* __restrict__ eiPtr,
                                                 const int* __restrict__ flag,
                                                 int* __restrict__ counts) {
  int e = blockIdx.x * 256 + threadIdx.x;
  if (e >= N_EDGES) return;
  int d = load_idx(eiPtr, flag, (long long)N_EDGES + e);
  atomicAdd(&counts[d], 1);
}

__global__ __launch_bounds__(256) void scan1(const int* __restrict__ counts,
                                             int* __restrict__ partial,
                                             int* __restrict__ blockSums) {
  __shared__ int lds[256];
  const int tid = threadIdx.x;
  const int idx = blockIdx.x * 1024 + tid * 4;
  int c0 = 0, c1 = 0, c2 = 0, c3 = 0;
  if (idx + 3 < N_NODES) {
    int4 c = *(const int4*)&counts[idx];
    c0 = c.x; c1 = c.y; c2 = c.z; c3 = c.w;
  } else {
    if (idx     < N_NODES) c0 = counts[idx];
    if (idx + 1 < N_NODES) c1 = counts[idx + 1];
    if (idx + 2 < N_NODES) c2 = counts[idx + 2];
    if (idx + 3 < N_NODES) c3 = counts[idx + 3];
  }
  int s0 = c0, s1 = s0 + c1, s2 = s1 + c2, s3 = s2 + c3;
  lds[tid] = s3;
  __syncthreads();
  for (int off = 1; off < 256; off <<= 1) {
    int t = (tid >= off) ? lds[tid - off] : 0;
    __syncthreads();
    lds[tid] += t;
    __syncthreads();
  }
  int excl = lds[tid] - s3;
  if (idx     < N_NODES) partial[idx]     = excl;
  if (idx + 1 < N_NODES) partial[idx + 1] = excl + s0;
  if (idx + 2 < N_NODES) partial[idx + 2] = excl + s1;
  if (idx + 3 < N_NODES) partial[idx + 3] = excl + s2;
  if (tid == 255) blockSums[blockIdx.x] = lds[255];
}

__global__ void scan2(int* __restrict__ blockSums) {
  __shared__ int lds[256];
  const int tid = threadIdx.x;
  lds[tid] = (tid < SCAN_NBLK) ? blockSums[tid] : 0;
  __syncthreads();
  int own = lds[tid];
  for (int off = 1; off < 256; off <<= 1) {
    int t = (tid >= off) ? lds[tid - off] : 0;
    __syncthreads();
    lds[tid] += t;
    __syncthreads();
  }
  if (tid < SCAN_NBLK) blockSums[tid] = lds[tid] - own;  // exclusive
}

__global__ __launch_bounds__(256) void scan3(int* __restrict__ rowPtr,
                                             const int* __restrict__ blockSums,
                                             int* __restrict__ cursor,
                                             int* __restrict__ bucketCursor) {
  int i = blockIdx.x * 256 + threadIdx.x;
  if (i >= N_NODES) return;
  int v = rowPtr[i] + blockSums[i >> 10];
  rowPtr[i] = v;
  cursor[i] = v;
  if ((i & 511) == 0) bucketCursor[i >> 9] = v;
  if (i == 0) rowPtr[N_NODES] = N_EDGES;
}

// Phase 1: bin edges by dst>>9 into bucket-grouped tmp (int4{src,dst,wbits,0}).
__global__ __launch_bounds__(256) void binpass(const void* __restrict__ eiPtr,
                                               const int* __restrict__ flag,
                                               const float* __restrict__ ew,
                                               int* __restrict__ bucketCursor,
                                               int4* __restrict__ tmp) {
  __shared__ int cnt[NBUK];
  __shared__ int base[NBUK];
  const int tid = threadIdx.x;
  const long long chunk0 = (long long)blockIdx.x * BIN_EPB;
  for (int i = tid; i < NBUK; i += 256) cnt[i] = 0;
  __syncthreads();
  int s[8], d[8], wb[8], rk[8];
  const bool i64 = (*flag != 0);
  #pragma unroll
  for (int j = 0; j < 8; ++j) {
    long long e = chunk0 + j * 256 + tid;
    rk[j] = -1;
    if (e < N_EDGES) {
      if (i64) {
        const long long* ei = (const long long*)eiPtr;
        s[j] = (int)ei[e]; d[j] = (int)ei[N_EDGES + e];
      } else {
        const int* ei = (const int*)eiPtr;
        s[j] = ei[e]; d[j] = ei[N_EDGES + e];
      }
      wb[j] = __float_as_int(ew[e]);
      rk[j] = atomicAdd(&cnt[d[j] >> 9], 1);
    }
  }
  __syncthreads();
  for (int b = tid; b < NBUK; b += 256) {
    int c = cnt[b];
    base[b] = c ? atomicAdd(&bucketCursor[b], c) : 0;
  }
  __syncthreads();
  #pragma unroll
  for (int j = 0; j < 8; ++j) {
    if (rk[j] >= 0) {
      int4 r; r.x = s[j]; r.y = d[j]; r.z = wb[j]; r.w = 0;
      tmp[base[d[j] >> 9] + rk[j]] = r;
    }
  }
}

// Phase 2: one block per bucket; scatter within the bucket's L2-hot CSR slice.
__global__ __launch_bounds__(256) void place(const int4* __restrict__ tmp,
                                             const int* __restrict__ rowPtr,
                                             int* __restrict__ cursor,
                                             int2* __restrict__ csrSW) {
  const int b = blockIdx.x;
  const int beg = rowPtr[b << 9];
  int endNode = (b + 1) << 9;
  if (endNode > N_NODES) endNode = N_NODES;
  const int end = rowPtr[endNode];
  for (int i = beg + threadIdx.x; i < end; i += 256) {
    int4 e = tmp[i];
    int pos = atomicAdd(&cursor[e.y], 1);
    int2 r; r.x = e.x; r.y = e.z;
    csrSW[pos] = r;
  }
}

// ---- pull aggregation: out[n] = sum_{e: dst=n} w_e * h[src_e] ---------------

__global__ __launch_bounds__(256) void pull_agg(const float* __restrict__ h,
                                                const int* __restrict__ rowPtr,
                                                const int2* __restrict__ csrSW,
                                                float* __restrict__ out) {
  int gtid = blockIdx.x * 256 + threadIdx.x;
  int n = gtid >> 6, lane = gtid & 63;
  if (n >= N_NODES) return;
  int beg = rowPtr[n], end = rowPtr[n + 1];
  float acc = 0.f;
  int i = beg;
  for (; i + 2 <= end; i += 2) {
    int2 a = csrSW[i];
    int2 b = csrSW[i + 1];
    float va = h[a.x * 64 + lane];
    float vb = h[b.x * 64 + lane];
    acc += __int_as_float(a.y) * va;
    acc += __int_as_float(b.y) * vb;
  }
  if (i < end) {
    int2 a = csrSW[i];
    acc += __int_as_float(a.y) * h[a.x * 64 + lane];
  }
  out[n * 64 + lane] = acc;
}

// ---- GEMM: C[N][64] = relu_in(A)[N][64] @ W + (bias?) (opt relu out) --------

template<bool RELU_IN, bool ADD_BIAS, bool RELU_OUT>
__global__ __launch_bounds__(256) void gemm64(const float* A,
                                              const float* __restrict__ W,
                                              const float* __restrict__ b,
                                              float* C, int N) {
  __shared__ float Wt[64][68];
  __shared__ float At[64][68];
  const int tid = threadIdx.x;
  const int rowBase = blockIdx.x * 64;

  for (int i = tid; i < 4096; i += 256) {
    int k = i >> 6, c = i & 63;
    Wt[c][k] = W[i];
  }
  const float4* A4 = (const float4*)A;
  #pragma unroll
  for (int j = 0; j < 4; ++j) {
    int t4 = tid + j * 256;
    int g4 = rowBase * 16 + t4;
    float4 v = make_float4(0.f, 0.f, 0.f, 0.f);
    if (g4 < N * 16) v = A4[g4];
    if (RELU_IN) {
      v.x = fmaxf(v.x, 0.f); v.y = fmaxf(v.y, 0.f);
      v.z = fmaxf(v.z, 0.f); v.w = fmaxf(v.w, 0.f);
    }
    int r = t4 >> 4, k4 = t4 & 15;
    *(float4*)&At[r][k4 * 4] = v;
  }
  __syncthreads();

  const int c = tid & 63;
  const int r0 = (tid >> 6) * 16;
  float acc[16];
  #pragma unroll
  for (int i = 0; i < 16; ++i) acc[i] = 0.f;

  for (int k0 = 0; k0 < 64; k0 += 4) {
    float4 w = *(const float4*)&Wt[c][k0];
    #pragma unroll
    for (int i = 0; i < 16; ++i) {
      float4 a = *(const float4*)&At[r0 + i][k0];
      acc[i] += a.x * w.x + a.y * w.y + a.z * w.z + a.w * w.w;
    }
  }

  const float bias = ADD_BIAS ? b[c] : 0.f;
  #pragma unroll
  for (int i = 0; i < 16; ++i) {
    int row = rowBase + r0 + i;
    if (row < N) {
      float v = acc[i] + bias;
      if (RELU_OUT) v = fmaxf(v, 0.f);
      C[row * 64 + c] = v;
    }
  }
}

// ---- layer-3 GEMM with fused segment-max pooling epilogue -------------------

__global__ __launch_bounds__(256) void gemm64_pool(const float* A,
                                                   const float* __restrict__ W,
                                                   const float* __restrict__ b,
                                                   const void* __restrict__ bPtr,
                                                   const int* __restrict__ flag,
                                                   unsigned* __restrict__ pooled,
                                                   int N) {
  __shared__ float Wt[64][68];
  __shared__ float At[64][68];
  const int tid = threadIdx.x;
  const int rowBase = blockIdx.x * 64;

  for (int i = tid; i < 4096; i += 256) {
    int k = i >> 6, c = i & 63;
    Wt[c][k] = W[i];
  }
  const float4* A4 = (const float4*)A;
  #pragma unroll
  for (int j = 0; j < 4; ++j) {
    int t4 = tid + j * 256;
    int g4 = rowBase * 16 + t4;
    float4 v = make_float4(0.f, 0.f, 0.f, 0.f);
    if (g4 < N * 16) v = A4[g4];
    int r = t4 >> 4, k4 = t4 & 15;
    *(float4*)&At[r][k4 * 4] = v;
  }
  __syncthreads();

  const int c = tid & 63;
  const int r0 = (tid >> 6) * 16;
  float acc[16];
  #pragma unroll
  for (int i = 0; i < 16; ++i) acc[i] = 0.f;

  for (int k0 = 0; k0 < 64; k0 += 4) {
    float4 w = *(const float4*)&Wt[c][k0];
    #pragma unroll
    for (int i = 0; i < 16; ++i) {
      float4 a = *(const float4*)&At[r0 + i][k0];
      acc[i] += a.x * w.x + a.y * w.y + a.z * w.z + a.w * w.w;
    }
  }

  // epilogue: run-length max over sorted batch, then atomicMax per run
  const float bias = b[c];
  const int row0 = rowBase + r0;
  if (row0 < N) {
    int curg = load_idx(bPtr, flag, row0);
    float best = acc[0] + bias;
    #pragma unroll
    for (int i = 1; i < 16; ++i) {
      int row = row0 + i;
      if (row >= N) break;
      int g = load_idx(bPtr, flag, row);
      float v = acc[i] + bias;
      if (g != curg) {
        atomicMax(&pooled[curg * 64 + c], f2ord(best));
        curg = g; best = v;
      } else {
        best = fmaxf(best, v);
      }
    }
    atomicMax(&pooled[curg * 64 + c], f2ord(best));
  }
}

// ---- fallback path (small ws): bias-init + atomic scatter -------------------

__global__ __launch_bounds__(256) void init_bias(float* __restrict__ agg,
                                                 const float* __restrict__ b, int n4) {
  int i = blockIdx.x * 256 + threadIdx.x;
  if (i >= n4) return;
  ((float4*)agg)[i] = ((const float4*)b)[i & 15];
}

__global__ __launch_bounds__(256) void scatter_add(const float* __restrict__ h,
                                                   const void* __restrict__ eiPtr,
                                                   const int* __restrict__ flag,
                                                   const float* __restrict__ ew,
                                                   float* __restrict__ agg) {
  int gtid = blockIdx.x * 256 + threadIdx.x;
  int e = gtid >> 6, lane = gtid & 63;
  if (e >= N_EDGES) return;
  int s = load_idx(eiPtr, flag, e);
  int d = load_idx(eiPtr, flag, (long long)N_EDGES + e);
  atomicAdd(&agg[d * 64 + lane], ew[e] * h[s * 64 + lane]);
}

__global__ __launch_bounds__(256) void seg_max(const float* __restrict__ h,
                                               const void* __restrict__ bPtr,
                                               const int* __restrict__ flag,
                                               unsigned* __restrict__ pooled) {
  int gtid = blockIdx.x * 256 + threadIdx.x;
  int n = gtid >> 6, lane = gtid & 63;
  if (n >= N_NODES) return;
  int g = load_idx(bPtr, flag, n);
  atomicMax(&pooled[g * 64 + lane], f2ord(h[n * 64 + lane]));
}

// ---- BatchNorm + linear head ------------------------------------------------

__global__ __launch_bounds__(256) void bn_head(const unsigned* __restrict__ pooled,
                                               const float* __restrict__ gamma,
                                               const float* __restrict__ beta,
                                               const float* __restrict__ linW,
                                               const float* __restrict__ linb,
                                               float* __restrict__ out) {
  __shared__ float P[NGRAPHS][64 + 1];
  __shared__ float mean_s[64], rstd_s[64];
  const int tid = threadIdx.x;

  for (int i = tid; i < NGRAPHS * 64; i += 256) {
    P[i >> 6][i & 63] = ord2f(pooled[i]);
  }
  __syncthreads();

  if (tid < 64) {
    float s = 0.f, ss = 0.f;
    for (int g = 0; g < NGRAPHS; ++g) {
      float v = P[g][tid];
      s += v; ss += v * v;
    }
    float m = s / (float)NGRAPHS;
    float var = ss / (float)NGRAPHS - m * m;
    mean_s[tid] = m;
    rstd_s[tid] = rsqrtf(var + BN_EPS);
  }
  __syncthreads();

  float acc = linb[0];
  #pragma unroll 8
  for (int c = 0; c < 64; ++c) {
    float normed = (P[tid][c] - mean_s[c]) * rstd_s[c] * gamma[c] + beta[c];
    acc += normed * linW[c];
  }
  out[tid] = acc;
}

// ---- launch -----------------------------------------------------------------

extern "C" void kernel_launch(void* const* d_in, const int* in_sizes, int n_in,
                              void* d_out, int out_size, void* d_ws, size_t ws_size,
                              hipStream_t stream) {
  const float* x     = (const float*)d_in[0];
  const void*  ei    = d_in[1];
  const float* ew    = (const float*)d_in[2];
  const void*  batch = d_in[3];
  const float* W1    = (const float*)d_in[4];
  const float* b1    = (const float*)d_in[5];
  const float* W2    = (const float*)d_in[6];
  const float* b2    = (const float*)d_in[7];
  const float* W3    = (const float*)d_in[8];
  const float* b3    = (const float*)d_in[9];
  const float* gamma = (const float*)d_in[10];
  const float* beta  = (const float*)d_in[11];
  const float* linW  = (const float*)d_in[12];
  const float* linb  = (const float*)d_in[13];

  char* ws = (char*)d_ws;
  const size_t MAT = (size_t)N_NODES * 64 * sizeof(float);          // 25.6 MB
  const size_t CSR = (size_t)N_EDGES * sizeof(int2);                // 12.8 MB
  const size_t PTR = ((size_t)(N_NODES + 1) * sizeof(int) + 255) & ~(size_t)255;

  size_t off = 0;
  float* t      = (float*)(ws + off); off += MAT;   // also CSR-build tmp (int4/edge)
  float* u      = (float*)(ws + off); off += MAT;
  int2*  csrSW  = (int2*)(ws + off); off += CSR;
  int*   rowPtr = (int*)(ws + off);  off += PTR;
  int*   cursor = (int*)(ws + off);  off += PTR;
  int*   bsums  = (int*)(ws + off);  off += 1024;
  int*   bukCur = (int*)(ws + off);  off += 1024;
  unsigned* pooled = (unsigned*)(ws + off); off += (size_t)NGRAPHS * 64 * sizeof(unsigned);
  int*   flag   = (int*)(ws + off);  off += 256;
  const bool csrPath = (ws_size >= off);

  const int gemmBlocks = (N_NODES + 63) / 64;
  const int edgeBlocks = (N_EDGES + 255) / 256;
  const int nodeWaveBlocks = (N_NODES * 64) / 256;   // 25000

  detect_i64<<<1, 64, 0, stream>>>((const unsigned*)ei, flag);

  if (csrPath) {
    int4* tmp = (int4*)t;   // 1.6M * 16B = 25.6 MB, dead until layer-2 pull
    // ---- build CSR (counting sort, L2-friendly) ----
    hipMemsetAsync(cursor, 0, (size_t)N_NODES * sizeof(int), stream);
    edge_hist<<<edgeBlocks, 256, 0, stream>>>(ei, flag, cursor);
    scan1<<<SCAN_NBLK, 256, 0, stream>>>(cursor, rowPtr, bsums);
    scan2<<<1, 256, 0, stream>>>(bsums);
    scan3<<<(N_NODES + 255) / 256, 256, 0, stream>>>(rowPtr, bsums, cursor, bukCur);
    binpass<<<BIN_BLOCKS, 256, 0, stream>>>(ei, flag, ew, bukCur, tmp);
    place<<<NBUK, 256, 0, stream>>>(tmp, rowPtr, cursor, csrSW);

    // layer 1: u = A·x ; u = relu(u@W1 + b1)
    pull_agg<<<nodeWaveBlocks, 256, 0, stream>>>(x, rowPtr, csrSW, u);
    gemm64<false, true, true><<<gemmBlocks, 256, 0, stream>>>(u, W1, b1, u, N_NODES);
    // layer 2
    pull_agg<<<nodeWaveBlocks, 256, 0, stream>>>(u, rowPtr, csrSW, t);
    gemm64<false, true, true><<<gemmBlocks, 256, 0, stream>>>(t, W2, b2, t, N_NODES);
    // layer 3: pull, then GEMM with fused bias + segment-max pooling
    pull_agg<<<nodeWaveBlocks, 256, 0, stream>>>(t, rowPtr, csrSW, u);
    hipMemsetAsync(pooled, 0, (size_t)NGRAPHS * 64 * sizeof(unsigned), stream);
    gemm64_pool<<<gemmBlocks, 256, 0, stream>>>(u, W3, b3, batch, flag, pooled, N_NODES);

    bn_head<<<1, 256, 0, stream>>>(pooled, gamma, beta, linW, linb, (float*)d_out);
  } else {
    // ---- fallback: atomic scatter path ----
    float* h   = t;
    float* agg = u;
    unsigned* pooled2 = (unsigned*)(ws + 2 * MAT);
    int* flag2 = (int*)(ws + 2 * MAT + (size_t)NGRAPHS * 64 * sizeof(unsigned));
    detect_i64<<<1, 64, 0, stream>>>((const unsigned*)ei, flag2);
    const int n4 = N_NODES * 16;
    const int initBlocks = (n4 + 255) / 256;
    const int scatBlocks = (N_EDGES * 64) / 256;

    gemm64<false, false, false><<<gemmBlocks, 256, 0, stream>>>(x, W1, b1, h, N_NODES);
    init_bias<<<initBlocks, 256, 0, stream>>>(agg, b1, n4);
    scatter_add<<<scatBlocks, 256, 0, stream>>>(h, ei, flag2, ew, agg);
    gemm64<true, false, false><<<gemmBlocks, 256, 0, stream>>>(agg, W2, b2, h, N_NODES);
    init_bias<<<initBlocks, 256, 0, stream>>>(agg, b2, n4);
    scatter_add<<<scatBlocks, 256, 0, stream>>>(h, ei, flag2, ew, agg);
    gemm64<true, false, false><<<gemmBlocks, 256, 0, stream>>>(agg, W3, b3, h, N_NODES);
    init_bias<<<initBlocks, 256, 0, stream>>>(agg, b3, n4);
    scatter_add<<<scatBlocks, 256, 0, stream>>>(h, ei, flag2, ew, agg);

    hipMemsetAsync(pooled2, 0, (size_t)NGRAPHS * 64 * sizeof(unsigned), stream);
    seg_max<<<nodeWaveBlocks, 256, 0, stream>>>(agg, batch, flag2, pooled2);
    bn_head<<<1, 256, 0, stream>>>(pooled2, gamma, beta, linW, linb, (float*)d_out);
  }
}

// Round 4
// 365.697 us; speedup vs baseline: 3.3139x; 1.4371x over previous
//
#include <hip/hip_runtime.h>

#define N_NODES 100000
#define N_EDGES 1600000
#define NGRAPHS 256
#define BN_EPS 1e-5f
#define NBUK ((N_NODES + 511) >> 9)           // 196 buckets of 512 dst nodes
#define BIN_EPB 2048                          // edges per binning block
#define BIN_BLOCKS ((N_EDGES + BIN_EPB - 1) / BIN_EPB)  // 782

// ---- helpers ----------------------------------------------------------------

__device__ __forceinline__ unsigned f2ord(float f) {
  unsigned u = __float_as_uint(f);
  return (u & 0x80000000u) ? ~u : (u | 0x80000000u);
}

__device__ __forceinline__ float ord2f(unsigned u) {
  unsigned bits = (u & 0x80000000u) ? (u ^ 0x80000000u) : ~u;
  return __uint_as_float(bits);
}

// Detect whether edge_index is int64 (high dwords all zero) or int32.
__global__ void detect_i64(const unsigned* __restrict__ ei, int* __restrict__ flag) {
  if (blockIdx.x == 0 && threadIdx.x == 0) {
    int f = 1;
    for (int i = 1; i < 64; i += 2) {
      if (ei[i] != 0u) { f = 0; break; }
    }
    *flag = f;
  }
}

__device__ __forceinline__ int load_idx(const void* p, const int* flag, long long i) {
  return (*flag) ? (int)((const long long*)p)[i] : ((const int*)p)[i];
}

// ---- CSR build (bucketed counting sort, no global per-node scan) ------------

// Pass A: bucket-level histogram (196 counters), 1 global atomic per bucket/block.
__global__ __launch_bounds__(256) void bucket_hist(const void* __restrict__ eiPtr,
                                                   const int* __restrict__ flag,
                                                   int* __restrict__ bucketCount) {
  __shared__ int cnt[NBUK];
  const int tid = threadIdx.x;
  for (int i = tid; i < NBUK; i += 256) cnt[i] = 0;
  __syncthreads();
  const long long chunk0 = (long long)blockIdx.x * BIN_EPB;
  const bool i64 = (*flag != 0);
  #pragma unroll
  for (int j = 0; j < 8; ++j) {
    long long e = chunk0 + j * 256 + tid;
    if (e < N_EDGES) {
      int d = i64 ? (int)((const long long*)eiPtr)[N_EDGES + e]
                  : ((const int*)eiPtr)[N_EDGES + e];
      atomicAdd(&cnt[d >> 9], 1);
    }
  }
  __syncthreads();
  for (int b = tid; b < NBUK; b += 256) {
    int c = cnt[b];
    if (c) atomicAdd(&bucketCount[b], c);
  }
}

// Pass B: exclusive scan of 196 bucket counts (1 block).
__global__ void bucket_scan(const int* __restrict__ bucketCount,
                            int* __restrict__ bucketBase,
                            int* __restrict__ bucketCursor,
                            int* __restrict__ rowPtr) {
  __shared__ int lds[256];
  const int tid = threadIdx.x;
  lds[tid] = (tid < NBUK) ? bucketCount[tid] : 0;
  __syncthreads();
  int own = lds[tid];
  for (int off = 1; off < 256; off <<= 1) {
    int t = (tid >= off) ? lds[tid - off] : 0;
    __syncthreads();
    lds[tid] += t;
    __syncthreads();
  }
  int excl = lds[tid] - own;
  if (tid < NBUK) { bucketBase[tid] = excl; bucketCursor[tid] = excl; }
  if (tid == 0) { bucketBase[NBUK] = N_EDGES; rowPtr[N_NODES] = N_EDGES; }
}

// Pass C: bin edges by dst>>9 into bucket-grouped tmp (int4{src,dst,wbits,0}).
__global__ __launch_bounds__(256) void binpass(const void* __restrict__ eiPtr,
                                               const int* __restrict__ flag,
                                               const float* __restrict__ ew,
                                               int* __restrict__ bucketCursor,
                                               int4* __restrict__ tmp) {
  __shared__ int cnt[NBUK];
  __shared__ int base[NBUK];
  const int tid = threadIdx.x;
  const long long chunk0 = (long long)blockIdx.x * BIN_EPB;
  for (int i = tid; i < NBUK; i += 256) cnt[i] = 0;
  __syncthreads();
  int s[8], d[8], wb[8], rk[8];
  const bool i64 = (*flag != 0);
  #pragma unroll
  for (int j = 0; j < 8; ++j) {
    long long e = chunk0 + j * 256 + tid;
    rk[j] = -1;
    if (e < N_EDGES) {
      if (i64) {
        const long long* ei = (const long long*)eiPtr;
        s[j] = (int)ei[e]; d[j] = (int)ei[N_EDGES + e];
      } else {
        const int* ei = (const int*)eiPtr;
        s[j] = ei[e]; d[j] = ei[N_EDGES + e];
      }
      wb[j] = __float_as_int(ew[e]);
      rk[j] = atomicAdd(&cnt[d[j] >> 9], 1);
    }
  }
  __syncthreads();
  for (int b = tid; b < NBUK; b += 256) {
    int c = cnt[b];
    base[b] = c ? atomicAdd(&bucketCursor[b], c) : 0;
  }
  __syncthreads();
  #pragma unroll
  for (int j = 0; j < 8; ++j) {
    if (rk[j] >= 0) {
      int4 r; r.x = s[j]; r.y = d[j]; r.z = wb[j]; r.w = 0;
      tmp[base[d[j] >> 9] + rk[j]] = r;
    }
  }
}

// Pass D: one block per bucket. Local hist(512) + LDS scan -> rowPtr slice,
// then scatter bucket slice into csrSW within the L2-hot window.
__global__ __launch_bounds__(256) void place2(const int4* __restrict__ tmp,
                                              const int* __restrict__ bucketBase,
                                              int* __restrict__ rowPtr,
                                              int2* __restrict__ csrSW) {
  __shared__ int cnt[512];
  __shared__ int sc[256];
  __shared__ int cur[512];
  const int b = blockIdx.x;
  const int tid = threadIdx.x;
  const int beg = bucketBase[b];
  const int end = bucketBase[b + 1];
  cnt[tid] = 0; cnt[tid + 256] = 0;
  __syncthreads();
  for (int i = beg + tid; i < end; i += 256) {
    atomicAdd(&cnt[tmp[i].y & 511], 1);
  }
  __syncthreads();
  // exclusive scan of 512 via pairs
  int c0 = cnt[2 * tid], c1 = cnt[2 * tid + 1];
  int pairSum = c0 + c1;
  sc[tid] = pairSum;
  __syncthreads();
  for (int off = 1; off < 256; off <<= 1) {
    int t = (tid >= off) ? sc[tid - off] : 0;
    __syncthreads();
    sc[tid] += t;
    __syncthreads();
  }
  int exclPair = sc[tid] - pairSum;           // exclusive over pairs
  int base0 = beg + exclPair;
  int base1 = base0 + c0;
  int g0 = (b << 9) + 2 * tid;
  if (g0 < N_NODES)     rowPtr[g0]     = base0;
  if (g0 + 1 < N_NODES) rowPtr[g0 + 1] = base1;
  cur[2 * tid] = base0;
  cur[2 * tid + 1] = base1;
  __syncthreads();
  for (int i = beg + tid; i < end; i += 256) {
    int4 e = tmp[i];
    int pos = atomicAdd(&cur[e.y & 511], 1);
    int2 r; r.x = e.x; r.y = e.z;
    csrSW[pos] = r;
  }
}

// ---- pull aggregation v2: coalesced meta + shfl-broadcast, 8-deep gathers ---

__global__ __launch_bounds__(256) void pull_agg(const float* __restrict__ h,
                                                const int* __restrict__ rowPtr,
                                                const int2* __restrict__ csrSW,
                                                float* __restrict__ out) {
  int gtid = blockIdx.x * 256 + threadIdx.x;
  int n = gtid >> 6, lane = gtid & 63;
  if (n >= N_NODES) return;
  const int beg = rowPtr[n], end = rowPtr[n + 1];
  float acc = 0.f;
  for (int base = beg; base < end; base += 64) {
    const int m = min(64, end - base);
    // coalesced: lane i grabs edge record base+i (clamped)
    int idx = base + (lane < m ? lane : m - 1);
    int2 meta = csrSW[idx];
    int src = meta.x;
    float w = __int_as_float(meta.y);
    int i = 0;
    for (; i + 8 <= m; i += 8) {
      float v[8], wv[8];
      #pragma unroll
      for (int j = 0; j < 8; ++j) {
        int s = __shfl(src, i + j);
        wv[j] = __shfl(w, i + j);
        v[j] = h[(long long)s * 64 + lane];
      }
      #pragma unroll
      for (int j = 0; j < 8; ++j) acc += wv[j] * v[j];
    }
    for (; i < m; ++i) {
      int s = __shfl(src, i);
      float wv = __shfl(w, i);
      acc += wv * h[(long long)s * 64 + lane];
    }
  }
  out[(long long)n * 64 + lane] = acc;
}

// ---- GEMM: C[N][64] = relu_in(A)[N][64] @ W + (bias?) (opt relu out) --------

template<bool RELU_IN, bool ADD_BIAS, bool RELU_OUT>
__global__ __launch_bounds__(256) void gemm64(const float* A,
                                              const float* __restrict__ W,
                                              const float* __restrict__ b,
                                              float* C, int N) {
  __shared__ float Wt[64][68];
  __shared__ float At[64][68];
  const int tid = threadIdx.x;
  const int rowBase = blockIdx.x * 64;

  for (int i = tid; i < 4096; i += 256) {
    int k = i >> 6, c = i & 63;
    Wt[c][k] = W[i];
  }
  const float4* A4 = (const float4*)A;
  #pragma unroll
  for (int j = 0; j < 4; ++j) {
    int t4 = tid + j * 256;
    int g4 = rowBase * 16 + t4;
    float4 v = make_float4(0.f, 0.f, 0.f, 0.f);
    if (g4 < N * 16) v = A4[g4];
    if (RELU_IN) {
      v.x = fmaxf(v.x, 0.f); v.y = fmaxf(v.y, 0.f);
      v.z = fmaxf(v.z, 0.f); v.w = fmaxf(v.w, 0.f);
    }
    int r = t4 >> 4, k4 = t4 & 15;
    *(float4*)&At[r][k4 * 4] = v;
  }
  __syncthreads();

  const int c = tid & 63;
  const int r0 = (tid >> 6) * 16;
  float acc[16];
  #pragma unroll
  for (int i = 0; i < 16; ++i) acc[i] = 0.f;

  for (int k0 = 0; k0 < 64; k0 += 4) {
    float4 w = *(const float4*)&Wt[c][k0];
    #pragma unroll
    for (int i = 0; i < 16; ++i) {
      float4 a = *(const float4*)&At[r0 + i][k0];
      acc[i] += a.x * w.x + a.y * w.y + a.z * w.z + a.w * w.w;
    }
  }

  const float bias = ADD_BIAS ? b[c] : 0.f;
  #pragma unroll
  for (int i = 0; i < 16; ++i) {
    int row = rowBase + r0 + i;
    if (row < N) {
      float v = acc[i] + bias;
      if (RELU_OUT) v = fmaxf(v, 0.f);
      C[row * 64 + c] = v;
    }
  }
}

// ---- layer-3 GEMM with fused segment-max pooling epilogue -------------------

__global__ __launch_bounds__(256) void gemm64_pool(const float* A,
                                                   const float* __restrict__ W,
                                                   const float* __restrict__ b,
                                                   const void* __restrict__ bPtr,
                                                   const int* __restrict__ flag,
                                                   unsigned* __restrict__ pooled,
                                                   int N) {
  __shared__ float Wt[64][68];
  __shared__ float At[64][68];
  const int tid = threadIdx.x;
  const int rowBase = blockIdx.x * 64;

  for (int i = tid; i < 4096; i += 256) {
    int k = i >> 6, c = i & 63;
    Wt[c][k] = W[i];
  }
  const float4* A4 = (const float4*)A;
  #pragma unroll
  for (int j = 0; j < 4; ++j) {
    int t4 = tid + j * 256;
    int g4 = rowBase * 16 + t4;
    float4 v = make_float4(0.f, 0.f, 0.f, 0.f);
    if (g4 < N * 16) v = A4[g4];
    int r = t4 >> 4, k4 = t4 & 15;
    *(float4*)&At[r][k4 * 4] = v;
  }
  __syncthreads();

  const int c = tid & 63;
  const int r0 = (tid >> 6) * 16;
  float acc[16];
  #pragma unroll
  for (int i = 0; i < 16; ++i) acc[i] = 0.f;

  for (int k0 = 0; k0 < 64; k0 += 4) {
    float4 w = *(const float4*)&Wt[c][k0];
    #pragma unroll
    for (int i = 0; i < 16; ++i) {
      float4 a = *(const float4*)&At[r0 + i][k0];
      acc[i] += a.x * w.x + a.y * w.y + a.z * w.z + a.w * w.w;
    }
  }

  // epilogue: run-length max over sorted batch, then atomicMax per run
  const float bias = b[c];
  const int row0 = rowBase + r0;
  if (row0 < N) {
    int curg = load_idx(bPtr, flag, row0);
    float best = acc[0] + bias;
    #pragma unroll
    for (int i = 1; i < 16; ++i) {
      int row = row0 + i;
      if (row >= N) break;
      int g = load_idx(bPtr, flag, row);
      float v = acc[i] + bias;
      if (g != curg) {
        atomicMax(&pooled[curg * 64 + c], f2ord(best));
        curg = g; best = v;
      } else {
        best = fmaxf(best, v);
      }
    }
    atomicMax(&pooled[curg * 64 + c], f2ord(best));
  }
}

// ---- fallback path (small ws): bias-init + atomic scatter -------------------

__global__ __launch_bounds__(256) void init_bias(float* __restrict__ agg,
                                                 const float* __restrict__ b, int n4) {
  int i = blockIdx.x * 256 + threadIdx.x;
  if (i >= n4) return;
  ((float4*)agg)[i] = ((const float4*)b)[i & 15];
}

__global__ __launch_bounds__(256) void scatter_add(const float* __restrict__ h,
                                                   const void* __restrict__ eiPtr,
                                                   const int* __restrict__ flag,
                                                   const float* __restrict__ ew,
                                                   float* __restrict__ agg) {
  int gtid = blockIdx.x * 256 + threadIdx.x;
  int e = gtid >> 6, lane = gtid & 63;
  if (e >= N_EDGES) return;
  int s = load_idx(eiPtr, flag, e);
  int d = load_idx(eiPtr, flag, (long long)N_EDGES + e);
  atomicAdd(&agg[d * 64 + lane], ew[e] * h[s * 64 + lane]);
}

__global__ __launch_bounds__(256) void seg_max(const float* __restrict__ h,
                                               const void* __restrict__ bPtr,
                                               const int* __restrict__ flag,
                                               unsigned* __restrict__ pooled) {
  int gtid = blockIdx.x * 256 + threadIdx.x;
  int n = gtid >> 6, lane = gtid & 63;
  if (n >= N_NODES) return;
  int g = load_idx(bPtr, flag, n);
  atomicMax(&pooled[g * 64 + lane], f2ord(h[n * 64 + lane]));
}

// ---- BatchNorm + linear head ------------------------------------------------

__global__ __launch_bounds__(256) void bn_head(const unsigned* __restrict__ pooled,
                                               const float* __restrict__ gamma,
                                               const float* __restrict__ beta,
                                               const float* __restrict__ linW,
                                               const float* __restrict__ linb,
                                               float* __restrict__ out) {
  __shared__ float P[NGRAPHS][64 + 1];
  __shared__ float mean_s[64], rstd_s[64];
  const int tid = threadIdx.x;

  for (int i = tid; i < NGRAPHS * 64; i += 256) {
    P[i >> 6][i & 63] = ord2f(pooled[i]);
  }
  __syncthreads();

  if (tid < 64) {
    float s = 0.f, ss = 0.f;
    for (int g = 0; g < NGRAPHS; ++g) {
      float v = P[g][tid];
      s += v; ss += v * v;
    }
    float m = s / (float)NGRAPHS;
    float var = ss / (float)NGRAPHS - m * m;
    mean_s[tid] = m;
    rstd_s[tid] = rsqrtf(var + BN_EPS);
  }
  __syncthreads();

  float acc = linb[0];
  #pragma unroll 8
  for (int c = 0; c < 64; ++c) {
    float normed = (P[tid][c] - mean_s[c]) * rstd_s[c] * gamma[c] + beta[c];
    acc += normed * linW[c];
  }
  out[tid] = acc;
}

// ---- launch -----------------------------------------------------------------

extern "C" void kernel_launch(void* const* d_in, const int* in_sizes, int n_in,
                              void* d_out, int out_size, void* d_ws, size_t ws_size,
                              hipStream_t stream) {
  const float* x     = (const float*)d_in[0];
  const void*  ei    = d_in[1];
  const float* ew    = (const float*)d_in[2];
  const void*  batch = d_in[3];
  const float* W1    = (const float*)d_in[4];
  const float* b1    = (const float*)d_in[5];
  const float* W2    = (const float*)d_in[6];
  const float* b2    = (const float*)d_in[7];
  const float* W3    = (const float*)d_in[8];
  const float* b3    = (const float*)d_in[9];
  const float* gamma = (const float*)d_in[10];
  const float* beta  = (const float*)d_in[11];
  const float* linW  = (const float*)d_in[12];
  const float* linb  = (const float*)d_in[13];

  char* ws = (char*)d_ws;
  const size_t MAT = (size_t)N_NODES * 64 * sizeof(float);          // 25.6 MB
  const size_t CSR = (size_t)N_EDGES * sizeof(int2);                // 12.8 MB
  const size_t PTR = ((size_t)(N_NODES + 1) * sizeof(int) + 255) & ~(size_t)255;

  size_t off = 0;
  float* t      = (float*)(ws + off); off += MAT;   // also CSR-build tmp (int4/edge)
  float* u      = (float*)(ws + off); off += MAT;
  int2*  csrSW  = (int2*)(ws + off); off += CSR;
  int*   rowPtr = (int*)(ws + off);  off += PTR;
  int*   bukCnt = (int*)(ws + off);  off += 1024;
  int*   bukBas = (int*)(ws + off);  off += 1024;   // NBUK+1 entries
  int*   bukCur = (int*)(ws + off);  off += 1024;
  unsigned* pooled = (unsigned*)(ws + off); off += (size_t)NGRAPHS * 64 * sizeof(unsigned);
  int*   flag   = (int*)(ws + off);  off += 256;
  const bool csrPath = (ws_size >= off);

  const int gemmBlocks = (N_NODES + 63) / 64;
  const int nodeWaveBlocks = (N_NODES * 64) / 256;   // 25000

  detect_i64<<<1, 64, 0, stream>>>((const unsigned*)ei, flag);

  if (csrPath) {
    int4* tmp = (int4*)t;   // 1.6M * 16B = 25.6 MB, dead until layer-2 pull
    // ---- build CSR (bucketed counting sort, no global per-node scan) ----
    hipMemsetAsync(bukCnt, 0, 1024, stream);
    bucket_hist<<<BIN_BLOCKS, 256, 0, stream>>>(ei, flag, bukCnt);
    bucket_scan<<<1, 256, 0, stream>>>(bukCnt, bukBas, bukCur, rowPtr);
    binpass<<<BIN_BLOCKS, 256, 0, stream>>>(ei, flag, ew, bukCur, tmp);
    place2<<<NBUK, 256, 0, stream>>>(tmp, bukBas, rowPtr, csrSW);

    // layer 1: u = A·x ; u = relu(u@W1 + b1)
    pull_agg<<<nodeWaveBlocks, 256, 0, stream>>>(x, rowPtr, csrSW, u);
    gemm64<false, true, true><<<gemmBlocks, 256, 0, stream>>>(u, W1, b1, u, N_NODES);
    // layer 2
    pull_agg<<<nodeWaveBlocks, 256, 0, stream>>>(u, rowPtr, csrSW, t);
    gemm64<false, true, true><<<gemmBlocks, 256, 0, stream>>>(t, W2, b2, t, N_NODES);
    // layer 3: pull, then GEMM with fused bias + segment-max pooling
    pull_agg<<<nodeWaveBlocks, 256, 0, stream>>>(t, rowPtr, csrSW, u);
    hipMemsetAsync(pooled, 0, (size_t)NGRAPHS * 64 * sizeof(unsigned), stream);
    gemm64_pool<<<gemmBlocks, 256, 0, stream>>>(u, W3, b3, batch, flag, pooled, N_NODES);

    bn_head<<<1, 256, 0, stream>>>(pooled, gamma, beta, linW, linb, (float*)d_out);
  } else {
    // ---- fallback: atomic scatter path ----
    float* h   = t;
    float* agg = u;
    unsigned* pooled2 = (unsigned*)(ws + 2 * MAT);
    int* flag2 = (int*)(ws + 2 * MAT + (size_t)NGRAPHS * 64 * sizeof(unsigned));
    detect_i64<<<1, 64, 0, stream>>>((const unsigned*)ei, flag2);
    const int n4 = N_NODES * 16;
    const int initBlocks = (n4 + 255) / 256;
    const int scatBlocks = (N_EDGES * 64) / 256;

    gemm64<false, false, false><<<gemmBlocks, 256, 0, stream>>>(x, W1, b1, h, N_NODES);
    init_bias<<<initBlocks, 256, 0, stream>>>(agg, b1, n4);
    scatter_add<<<scatBlocks, 256, 0, stream>>>(h, ei, flag2, ew, agg);
    gemm64<true, false, false><<<gemmBlocks, 256, 0, stream>>>(agg, W2, b2, h, N_NODES);
    init_bias<<<initBlocks, 256, 0, stream>>>(agg, b2, n4);
    scatter_add<<<scatBlocks, 256, 0, stream>>>(h, ei, flag2, ew, agg);
    gemm64<true, false, false><<<gemmBlocks, 256, 0, stream>>>(agg, W3, b3, h, N_NODES);
    init_bias<<<initBlocks, 256, 0, stream>>>(agg, b3, n4);
    scatter_add<<<scatBlocks, 256, 0, stream>>>(h, ei, flag2, ew, agg);

    hipMemsetAsync(pooled2, 0, (size_t)NGRAPHS * 64 * sizeof(unsigned), stream);
    seg_max<<<nodeWaveBlocks, 256, 0, stream>>>(agg, batch, flag2, pooled2);
    bn_head<<<1, 256, 0, stream>>>(pooled2, gamma, beta, linW, linb, (float*)d_out);
  }
}